// Round 2
// baseline (29784.595 us; speedup 1.0000x reference)
//
#include <hip/hip_runtime.h>
#include <hip/hip_bf16.h>
#include <hip/hip_fp16.h>

#define BB  512
#define TT  256
#define MM  81
#define HEE 256

// ---- workspace layout (float offsets) ----
#define OFF_W2AH   0          // half2[256][256]  (k-pair, j) encoder p1 weights
#define OFF_WE8    65536      // uint4[169][256]  encoder LSTM weights, 8 halves (4 gates x k-pair)
#define OFF_W2D1   238592     // half2[256][256]  decoder p1 weights
#define OFF_WD8    304128     // uint4[129][256]  decoder LSTM weights
#define OFF_ATTN   436224     // [512][81] attn_in
#define OFF_ENCW   477696     // [512][256] enc . W_fc[:256]
#define OFF_ENC    608768     // [512][256][256] input_encoded fp32
#define OFF_EPI    34163200   // half2[256 wg][256 h][256 t'] enc_proj interleaved (b0,b1)
#define WS_FLOATS  50940416

__device__ __forceinline__ float frcp(float x) { return __builtin_amdgcn_rcpf(x); }
__device__ __forceinline__ float fsig(float x) { return frcp(1.f + __expf(-x)); }
__device__ __forceinline__ float ftanh(float x) { return 1.f - 2.f * frcp(__expf(2.f * x) + 1.f); }

__device__ __forceinline__ void gate_fma(const uint4& wu, const float4& uv, float4& g0, float4& g1) {
  const __half2* wh = reinterpret_cast<const __half2*>(&wu);
  float2 if0 = __half22float2(wh[0]);   // (Wi[ke], Wf[ke])
  float2 go0 = __half22float2(wh[1]);   // (Wg[ke], Wo[ke])
  float2 if1 = __half22float2(wh[2]);   // (Wi[ko], Wf[ko])
  float2 go1 = __half22float2(wh[3]);   // (Wg[ko], Wo[ko])
  g0.x = fmaf(if0.x, uv.x, fmaf(if1.x, uv.z, g0.x));
  g0.y = fmaf(if0.y, uv.x, fmaf(if1.y, uv.z, g0.y));
  g0.z = fmaf(go0.x, uv.x, fmaf(go1.x, uv.z, g0.z));
  g0.w = fmaf(go0.y, uv.x, fmaf(go1.y, uv.z, g0.w));
  g1.x = fmaf(if0.x, uv.y, fmaf(if1.x, uv.w, g1.x));
  g1.y = fmaf(if0.y, uv.y, fmaf(if1.y, uv.w, g1.y));
  g1.z = fmaf(go0.x, uv.y, fmaf(go1.x, uv.w, g1.z));
  g1.w = fmaf(go0.y, uv.y, fmaf(go1.y, uv.w, g1.w));
}

// ---------------- weight prep: transpose + fp16 pack ----------------
__global__ void k_prep(const float* __restrict__ W_ah, const float* __restrict__ Wih_e,
                       const float* __restrict__ Whh_e, const float* __restrict__ W_d1,
                       const float* __restrict__ Wih_d, const float* __restrict__ Whh_d,
                       float* __restrict__ ws) {
  int idx = blockIdx.x * 512 + threadIdx.x;
  if (idx < 65536) {
    int k2 = idx >> 8, j = idx & 255;
    ((__half2*)(ws + OFF_W2AH))[idx] =
        __floats2half2_rn(W_ah[j * 512 + 2 * k2], W_ah[j * 512 + 2 * k2 + 1]);
    ((__half2*)(ws + OFF_W2D1))[idx] =
        __floats2half2_rn(W_d1[j * 768 + 2 * k2], W_d1[j * 768 + 2 * k2 + 1]);
  }
  if (idx < 43264) {  // 169*256
    int k2 = idx >> 8, j = idx & 255;
    auto we = [&](int g, int kk) -> float {
      if (kk < 81)  return Wih_e[(g * 256 + j) * 81 + kk];
      if (kk < 337) return Whh_e[(g * 256 + j) * 256 + (kk - 81)];
      return 0.f;
    };
    int ke = 2 * k2, ko = 2 * k2 + 1;
    union { __half2 h[4]; uint4 u; } w;
    w.h[0] = __floats2half2_rn(we(0, ke), we(1, ke));
    w.h[1] = __floats2half2_rn(we(2, ke), we(3, ke));
    w.h[2] = __floats2half2_rn(we(0, ko), we(1, ko));
    w.h[3] = __floats2half2_rn(we(2, ko), we(3, ko));
    ((uint4*)(ws + OFF_WE8))[idx] = w.u;
  }
  if (idx < 33024) {  // 129*256
    int k2 = idx >> 8, j = idx & 255;
    auto wd = [&](int g, int kk) -> float {
      if (kk == 0)  return Wih_d[g * 256 + j];
      if (kk < 257) return Whh_d[(g * 256 + j) * 256 + (kk - 1)];
      return 0.f;
    };
    int ke = 2 * k2, ko = 2 * k2 + 1;
    union { __half2 h[4]; uint4 u; } w;
    w.h[0] = __floats2half2_rn(wd(0, ke), wd(1, ke));
    w.h[1] = __floats2half2_rn(wd(2, ke), wd(3, ke));
    w.h[2] = __floats2half2_rn(wd(0, ko), wd(1, ko));
    w.h[3] = __floats2half2_rn(wd(2, ko), wd(3, ko));
    ((uint4*)(ws + OFF_WD8))[idx] = w.u;
  }
}

// ---------------- attn_in[b][m] ----------------
__global__ void k_attn(const float* __restrict__ x, const float* __restrict__ W_ai,
                       const float* __restrict__ b_ai, float* __restrict__ ws) {
  __shared__ float wai[256];
  const int b = blockIdx.x, tid = threadIdx.x;  // 128 threads
  wai[tid] = W_ai[tid];
  wai[128 + tid] = W_ai[128 + tid];
  __syncthreads();
  if (tid < MM) {
    float acc = b_ai[0];
    const float* xp = x + (size_t)b * TT * MM + tid;
    #pragma unroll 8
    for (int t = 0; t < TT; ++t) acc = fmaf(xp[t * MM], wai[t], acc);
    ws[OFF_ATTN + b * MM + tid] = acc;
  }
}

// ---------------- encoder: 512 threads, 2 batch rows, 256 steps ----------------
__global__ __launch_bounds__(512, 4) void k_encoder(
    const float* __restrict__ x, const float* __restrict__ b_ah,
    const float* __restrict__ W_a, const float* __restrict__ b_a,
    const float* __restrict__ bih_e, const float* __restrict__ bhh_e,
    float* __restrict__ ws) {
  __shared__ __align__(16) float hcat[1024];   // [h;c] packed: addr = 2k + b
  __shared__ __align__(16) float ubuf[680];    // [wi(81); h(256); pad]: addr = (k>>1)*4+(k&1)*2+b
  __shared__ __align__(16) float hpb[512];     // hid_proj packed: 2t+b
  __shared__ __align__(16) float wa2[256];
  __shared__ __align__(16) float pp[1024];     // p1 partials (kh*256+j)*2+b
  __shared__ float scp[4][2][96];
  __shared__ __align__(16) float gp[4096];     // [(kh*2+b)*256+j] float4
  __shared__ __align__(16) float ebias[1024];
  __shared__ float ebah[256];
  const int tid = threadIdx.x;
  const int j = tid & 255, kh = tid >> 8;
  const int b0 = blockIdx.x * 2, b1 = b0 + 1;

  if (tid < 256) {
    wa2[tid] = W_a[tid];
    ebah[tid] = b_ah[tid];
    float4 b4;
    b4.x = bih_e[tid] + bhh_e[tid];
    b4.y = bih_e[256 + tid] + bhh_e[256 + tid];
    b4.z = bih_e[512 + tid] + bhh_e[512 + tid];
    b4.w = bih_e[768 + tid] + bhh_e[768 + tid];
    ((float4*)ebias)[tid] = b4;
  }
  for (int i = tid; i < 1024; i += 512) hcat[i] = 0.f;
  for (int i = tid; i < 680; i += 512) ubuf[i] = 0.f;
  // p2 per-thread attn constants
  float ai0 = 0.f, ai1 = 0.f;
  {
    int m = tid & 127;
    if (m < MM) {
      ai0 = ws[OFF_ATTN + b0 * MM + m];
      ai1 = ws[OFF_ATTN + b1 * MM + m];
    }
  }
  const float bav = b_a[0];
  // p3 x prefetch (waves 0,1)
  float xc0 = 0.f, xc1 = 0.f;
  if (tid < 128) {
    int bb = (tid >= 64) ? b1 : b0;
    int lane = tid & 63;
    xc0 = x[((size_t)bb * TT) * MM + lane];
    xc1 = (lane < 17) ? x[((size_t)bb * TT) * MM + 64 + lane] : 0.f;
  }
  const __half2* __restrict__ Wah2 = (const __half2*)(ws + OFF_W2AH);
  const uint4* __restrict__ We8 = (const uint4*)(ws + OFF_WE8);
  __syncthreads();

  for (int t = 0; t < TT; ++t) {
    // ---- p1: hid_proj = [h;c].W_ah^T (k split by kh) ----
    {
      float a0 = 0.f, a1 = 0.f;
      const int kb = kh * 128;
      #pragma unroll 8
      for (int i = 0; i < 128; ++i) {
        int k2 = kb + i;
        float2 wf = __half22float2(Wah2[k2 * 256 + j]);
        float4 hv = *(const float4*)&hcat[k2 * 4];
        a0 = fmaf(wf.x, hv.x, fmaf(wf.y, hv.z, a0));
        a1 = fmaf(wf.x, hv.y, fmaf(wf.y, hv.w, a1));
      }
      pp[(kh * 256 + j) * 2 + 0] = a0;
      pp[(kh * 256 + j) * 2 + 1] = a1;
    }
    __syncthreads();
    if (tid < 256) {
      float h0 = pp[tid * 2] + pp[(256 + tid) * 2] + ebah[tid];
      float h1 = pp[tid * 2 + 1] + pp[(256 + tid) * 2 + 1] + ebah[tid];
      hpb[2 * tid + 0] = h0;
      hpb[2 * tid + 1] = h1;
    }
    __syncthreads();
    // ---- p2: score[m] partials over t-quarters ----
    {
      int m = tid & 127, tq = tid >> 7;
      if (m < MM) {
        float e0 = 0.f, e1 = 0.f;
        #pragma unroll 8
        for (int t2 = tq * 32; t2 < tq * 32 + 32; ++t2) {
          float4 hv = *(const float4*)&hpb[t2 * 4];
          float2 wv = *(const float2*)&wa2[t2 * 2];
          e0 += ftanh(hv.x + ai0) * wv.x + ftanh(hv.z + ai0) * wv.y;
          e1 += ftanh(hv.y + ai1) * wv.x + ftanh(hv.w + ai1) * wv.y;
        }
        scp[tq][0][m] = e0;
        scp[tq][1][m] = e1;
      }
    }
    __syncthreads();
    // ---- p3: softmax over m + wi (waves 0,1) ----
    if (tid < 128) {
      int wv_id = tid >> 6, lane = tid & 63;
      float v0 = scp[0][wv_id][lane] + scp[1][wv_id][lane] +
                 scp[2][wv_id][lane] + scp[3][wv_id][lane] + bav;
      float v1 = (lane < 17) ? scp[0][wv_id][64 + lane] + scp[1][wv_id][64 + lane] +
                               scp[2][wv_id][64 + lane] + scp[3][wv_id][64 + lane] + bav
                             : -1e30f;
      float mx = fmaxf(v0, v1);
      #pragma unroll
      for (int d = 1; d < 64; d <<= 1) mx = fmaxf(mx, __shfl_xor(mx, d));
      float e0 = __expf(v0 - mx);
      float e1 = (lane < 17) ? __expf(v1 - mx) : 0.f;
      float sm = e0 + e1;
      #pragma unroll
      for (int d = 1; d < 64; d <<= 1) sm += __shfl_xor(sm, d);
      float inv = frcp(sm);
      float w0 = e0 * inv * xc0;
      float w1 = e1 * inv * xc1;
      int m0 = lane, m1 = 64 + lane;
      ubuf[(m0 >> 1) * 4 + (m0 & 1) * 2 + wv_id] = w0;
      if (lane < 17) ubuf[(m1 >> 1) * 4 + (m1 & 1) * 2 + wv_id] = w1;
      if (t < 255) {
        int bb = wv_id ? b1 : b0;
        xc0 = x[((size_t)bb * TT + t + 1) * MM + lane];
        xc1 = (lane < 17) ? x[((size_t)bb * TT + t + 1) * MM + 64 + lane] : 0.f;
      }
    }
    __syncthreads();
    // ---- p4: LSTM gates (k split by kh) ----
    {
      float4 g0 = {0, 0, 0, 0}, g1 = {0, 0, 0, 0};
      const int kA = kh ? 85 : 0, kB = kh ? 169 : 85;
      #pragma unroll 4
      for (int k2 = kA; k2 < kB; ++k2) {
        uint4 wu = We8[k2 * 256 + j];
        float4 uv = *(const float4*)&ubuf[k2 * 4];
        gate_fma(wu, uv, g0, g1);
      }
      *(float4*)&gp[((kh * 2 + 0) * 256 + j) * 4] = g0;
      *(float4*)&gp[((kh * 2 + 1) * 256 + j) * 4] = g1;
    }
    __syncthreads();
    // ---- p4 reduce + state update ----
    {
      int b = kh;
      float4 ga = *(const float4*)&gp[((0 + b) * 256 + j) * 4];
      float4 gb = *(const float4*)&gp[((2 + b) * 256 + j) * 4];
      float4 bi = *(const float4*)&ebias[j * 4];
      float gi = ga.x + gb.x + bi.x, gf = ga.y + gb.y + bi.y;
      float gg = ga.z + gb.z + bi.z, go = ga.w + gb.w + bi.w;
      int cs = 256 + j;
      float cold = hcat[cs * 2 + b - ((cs & 1) ? 0 : 0)];  // addr = 2k+b
      cold = hcat[2 * cs + b];
      float c = fsig(gf) * cold + fsig(gi) * ftanh(gg);
      float h = fsig(go) * ftanh(c);
      hcat[2 * j + b] = h;
      hcat[2 * cs + b] = c;
      int us = 81 + j;
      ubuf[(us >> 1) * 4 + (us & 1) * 2 + b] = h;
      ws[OFF_ENC + (((size_t)(b ? b1 : b0) * TT + t) * HEE + j)] = h;
    }
    __syncthreads();
  }
}

// ---------------- encW[b][t] = enc[b,t,:] . W_fc[:256] ----------------
__global__ __launch_bounds__(256) void k_encw(const float* __restrict__ W_fc, float* __restrict__ ws) {
  const float* __restrict__ enc = ws + OFF_ENC;
  const int wv = threadIdx.x >> 6, lane = threadIdx.x & 63;
  float4 wfc = reinterpret_cast<const float4*>(W_fc)[lane];
  for (int r = blockIdx.x * 4 + wv; r < BB * TT; r += 4096) {
    float4 e = reinterpret_cast<const float4*>(enc + (size_t)r * HEE)[lane];
    float d = e.x * wfc.x + e.y * wfc.y + e.z * wfc.z + e.w * wfc.w;
    #pragma unroll
    for (int dd = 1; dd < 64; dd <<= 1) d += __shfl_xor(d, dd);
    if (lane == 0) ws[OFF_ENCW + r] = d;
  }
}

// ---------------- enc_proj interleaved fp16: epI[bg][h][t'] = half2(b0,b1) ----------------
__global__ __launch_bounds__(256) void k_encproj(const float* __restrict__ W_d1, float* __restrict__ ws) {
  __shared__ __align__(16) float le[16][256];
  const int tid = threadIdx.x;
  const int bg = blockIdx.x >> 5;
  const int t0 = (blockIdx.x & 31) * 8;
  const float* __restrict__ enc = ws + OFF_ENC;
  __half2* __restrict__ epI = (__half2*)(ws + OFF_EPI);
  #pragma unroll
  for (int p = 0; p < 2; ++p)
    #pragma unroll
    for (int rr = 0; rr < 8; ++rr)
      le[p * 8 + rr][tid] = enc[((size_t)(bg * 2 + p) * TT + (t0 + rr)) * HEE + tid];
  __syncthreads();
  const float4* wrow = (const float4*)(W_d1 + (size_t)tid * 768 + 512);
  float acc[16];
  #pragma unroll
  for (int r = 0; r < 16; ++r) acc[r] = 0.f;
  for (int e4 = 0; e4 < 64; ++e4) {
    float4 w = wrow[e4];
    #pragma unroll
    for (int r = 0; r < 16; ++r) {
      float4 ev = *(const float4*)&le[r][e4 * 4];
      acc[r] += ev.x * w.x + ev.y * w.y + ev.z * w.z + ev.w * w.w;
    }
  }
  #pragma unroll
  for (int rr = 0; rr < 8; ++rr)
    epI[((size_t)bg * 256 + tid) * 256 + (t0 + rr)] = __floats2half2_rn(acc[rr], acc[8 + rr]);
}

// ---------------- decoder: 512 threads, 2 batch rows, 255 steps ----------------
__global__ __launch_bounds__(512, 2) void k_decoder(
    const float* __restrict__ y_history, const float* __restrict__ b_d1,
    const float* __restrict__ W_d2, const float* __restrict__ b_d2,
    const float* __restrict__ W_fc, const float* __restrict__ b_fc,
    const float* __restrict__ bih_d, const float* __restrict__ bhh_d,
    const float* __restrict__ W_ff, const float* __restrict__ b_ff,
    float* __restrict__ ws, float* __restrict__ out) {
  __shared__ __align__(16) float hcat[1024];   // addr = 2k+b, k in [0,512)
  __shared__ __align__(16) float ubuf[516];    // [y; h(256); pad]
  __shared__ __align__(16) float ddp[512];     // d packed: 2h+b
  __shared__ __align__(16) float w2s[256];
  __shared__ __align__(16) float pp[1024];
  __shared__ __align__(16) float qp[1024];     // (hh*256+t')*2+b
  __shared__ __align__(16) float gp[4096];
  __shared__ __align__(16) float dbias[1024];
  __shared__ __align__(16) float awls[512];    // 2t+b
  __shared__ __align__(16) float cp[1024];
  __shared__ float red[3][8];
  const int tid = threadIdx.x;
  const int tp = tid & 255, hh = tid >> 8;
  const int lane = tid & 63, wv = tid >> 6;
  const int b0 = blockIdx.x * 2, b1 = b0 + 1;

  if (tid < 256) {
    w2s[tid] = W_d2[tid];
    float4 b4;
    b4.x = bih_d[tid] + bhh_d[tid];
    b4.y = bih_d[256 + tid] + bhh_d[256 + tid];
    b4.z = bih_d[512 + tid] + bhh_d[512 + tid];
    b4.w = bih_d[768 + tid] + bhh_d[768 + tid];
    ((float4*)dbias)[tid] = b4;
  }
  for (int i = tid; i < 1024; i += 512) hcat[i] = 0.f;
  for (int i = tid; i < 516; i += 512) ubuf[i] = 0.f;

  // enc_proj into registers: 128 half2 (b0,b1) for h in [hh*128, hh*128+128), col t'=tp
  const __half2* __restrict__ epI =
      (const __half2*)(ws + OFF_EPI) + (size_t)blockIdx.x * 65536;
  __half2 ep[128];
  #pragma unroll
  for (int i = 0; i < 128; ++i) ep[i] = epI[(hh * 128 + i) * 256 + tp];

  const float ew_reg = ws[OFF_ENCW + (size_t)(hh ? b1 : b0) * 256 + tp];
  float ynext = y_history[(size_t)(hh ? b1 : b0) * 255];
  const float bd1 = b_d1[tp];
  const float wfcy = W_fc[256], bfc = b_fc[0], bd2v = b_d2[0];
  const __half2* __restrict__ Wd2h = (const __half2*)(ws + OFF_W2D1);
  const uint4* __restrict__ Wd8 = (const uint4*)(ws + OFF_WD8);
  __syncthreads();

  for (int s = 0; s < 255; ++s) {
    // ---- p1: d = [h;c].W_d1hc^T ----
    {
      float a0 = 0.f, a1 = 0.f;
      const int kb = hh * 128;
      #pragma unroll 8
      for (int i = 0; i < 128; ++i) {
        int k2 = kb + i;
        float2 wf = __half22float2(Wd2h[k2 * 256 + tp]);
        float4 hv = *(const float4*)&hcat[k2 * 4];
        a0 = fmaf(wf.x, hv.x, fmaf(wf.y, hv.z, a0));
        a1 = fmaf(wf.x, hv.y, fmaf(wf.y, hv.w, a1));
      }
      pp[(hh * 256 + tp) * 2 + 0] = a0;
      pp[(hh * 256 + tp) * 2 + 1] = a1;
    }
    __syncthreads();
    if (tid < 256) {
      float d0 = pp[tid * 2] + pp[(256 + tid) * 2] + bd1;
      float d1 = pp[tid * 2 + 1] + pp[(256 + tid) * 2 + 1] + bd1;
      ddp[2 * tid + 0] = d0;
      ddp[2 * tid + 1] = d1;
    }
    __syncthreads();
    // ---- p2: score partials from register-resident enc_proj ----
    {
      float q0 = 0.f, q1 = 0.f;
      const int base = hh * 64;
      #pragma unroll
      for (int ii = 0; ii < 64; ++ii) {
        float4 dv = *(const float4*)&ddp[(base + ii) * 4];
        float2 wvv = *(const float2*)&w2s[(base + ii) * 2];
        float2 ea = __half22float2(ep[2 * ii]);
        float2 eb = __half22float2(ep[2 * ii + 1]);
        q0 += ftanh(ea.x + dv.x) * wvv.x + ftanh(eb.x + dv.z) * wvv.y;
        q1 += ftanh(ea.y + dv.y) * wvv.x + ftanh(eb.y + dv.w) * wvv.y;
      }
      qp[(hh * 256 + tp) * 2 + 0] = q0;
      qp[(hh * 256 + tp) * 2 + 1] = q1;
    }
    __syncthreads();
    // ---- p3: softmax over t' (group hh -> batch), y_tild ----
    {
      const int g = hh;
      float v = qp[tp * 2 + g] + qp[(256 + tp) * 2 + g] + bd2v;
      float mx = v;
      #pragma unroll
      for (int d = 1; d < 64; d <<= 1) mx = fmaxf(mx, __shfl_xor(mx, d));
      if (lane == 0) red[0][wv] = mx;
      __syncthreads();
      mx = fmaxf(fmaxf(red[0][g * 4 + 0], red[0][g * 4 + 1]),
                 fmaxf(red[0][g * 4 + 2], red[0][g * 4 + 3]));
      float e = __expf(v - mx);
      float den = e, num = e * ew_reg;
      #pragma unroll
      for (int d = 1; d < 64; d <<= 1) { den += __shfl_xor(den, d); num += __shfl_xor(num, d); }
      if (lane == 0) { red[1][wv] = den; red[2][wv] = num; }
      __syncthreads();
      den = red[1][g * 4 + 0] + red[1][g * 4 + 1] + red[1][g * 4 + 2] + red[1][g * 4 + 3];
      num = red[2][g * 4 + 0] + red[2][g * 4 + 1] + red[2][g * 4 + 2] + red[2][g * 4 + 3];
      float inv = frcp(den);
      float y = num * inv + ynext * wfcy + bfc;
      if (s == 254) awls[2 * tp + g] = e * inv;
      if (tp == 0) ubuf[g] = y;   // u slot k=0: addr = b
      if (s < 254) ynext = y_history[(size_t)(g ? b1 : b0) * 255 + s + 1];
    }
    __syncthreads();
    // ---- p5: decoder LSTM gates ----
    {
      float4 g0 = {0, 0, 0, 0}, g1 = {0, 0, 0, 0};
      const int kA = hh ? 65 : 0, kB = hh ? 129 : 65;
      #pragma unroll 4
      for (int k2 = kA; k2 < kB; ++k2) {
        uint4 wu = Wd8[k2 * 256 + tp];
        float4 uv = *(const float4*)&ubuf[k2 * 4];
        gate_fma(wu, uv, g0, g1);
      }
      *(float4*)&gp[((hh * 2 + 0) * 256 + tp) * 4] = g0;
      *(float4*)&gp[((hh * 2 + 1) * 256 + tp) * 4] = g1;
    }
    __syncthreads();
    // ---- p5 reduce + state update ----
    {
      int b = hh;
      float4 ga = *(const float4*)&gp[((0 + b) * 256 + tp) * 4];
      float4 gb = *(const float4*)&gp[((2 + b) * 256 + tp) * 4];
      float4 bi = *(const float4*)&dbias[tp * 4];
      float gi = ga.x + gb.x + bi.x, gf = ga.y + gb.y + bi.y;
      float gg = ga.z + gb.z + bi.z, go = ga.w + gb.w + bi.w;
      int cs = 256 + tp;
      float cold = hcat[2 * cs + b];
      float c = fsig(gf) * cold + fsig(gi) * ftanh(gg);
      float h = fsig(go) * ftanh(c);
      hcat[2 * tp + b] = h;
      hcat[2 * cs + b] = c;
      int us = 1 + tp;
      ubuf[(us >> 1) * 4 + (us & 1) * 2 + b] = h;
    }
    __syncthreads();
  }

  // ---- final: full ctx (last step aw) + output ----
  {
    float c0 = 0.f, c1 = 0.f;
    const float* __restrict__ e0p = ws + OFF_ENC + (size_t)b0 * TT * HEE;
    const float* __restrict__ e1p = ws + OFF_ENC + (size_t)b1 * TT * HEE;
    for (int t2 = hh * 128; t2 < hh * 128 + 128; ++t2) {
      float aw0 = awls[2 * t2], aw1 = awls[2 * t2 + 1];
      c0 = fmaf(aw0, e0p[(size_t)t2 * HEE + tp], c0);
      c1 = fmaf(aw1, e1p[(size_t)t2 * HEE + tp], c1);
    }
    cp[(hh * 256 + tp) * 2 + 0] = c0;
    cp[(hh * 256 + tp) * 2 + 1] = c1;
  }
  __syncthreads();
  {
    int b = hh;
    float ctx = cp[tp * 2 + b] + cp[(256 + tp) * 2 + b];
    float hfin = hcat[2 * tp + b];
    float p = hfin * W_ff[tp] + ctx * W_ff[256 + tp];
    #pragma unroll
    for (int d = 1; d < 64; d <<= 1) p += __shfl_xor(p, d);
    if (lane == 0) red[0][wv] = p;
  }
  __syncthreads();
  if (tid == 0)   out[b0] = red[0][0] + red[0][1] + red[0][2] + red[0][3] + b_ff[0];
  if (tid == 256) out[b1] = red[0][4] + red[0][5] + red[0][6] + red[0][7] + b_ff[0];
}

extern "C" void kernel_launch(void* const* d_in, const int* in_sizes, int n_in,
                              void* d_out, int out_size, void* d_ws, size_t ws_size,
                              hipStream_t stream) {
  if (ws_size < (size_t)WS_FLOATS * sizeof(float)) return;
  const float* x     = (const float*)d_in[0];
  const float* y_h   = (const float*)d_in[1];
  const float* W_ah  = (const float*)d_in[2];
  const float* b_ah  = (const float*)d_in[3];
  const float* W_ai  = (const float*)d_in[4];
  const float* b_ai  = (const float*)d_in[5];
  const float* W_a   = (const float*)d_in[6];
  const float* b_a   = (const float*)d_in[7];
  const float* Wih_e = (const float*)d_in[8];
  const float* Whh_e = (const float*)d_in[9];
  const float* bih_e = (const float*)d_in[10];
  const float* bhh_e = (const float*)d_in[11];
  const float* W_d1  = (const float*)d_in[12];
  const float* b_d1  = (const float*)d_in[13];
  const float* W_d2  = (const float*)d_in[14];
  const float* b_d2  = (const float*)d_in[15];
  const float* W_fc  = (const float*)d_in[16];
  const float* b_fc  = (const float*)d_in[17];
  const float* Wih_d = (const float*)d_in[18];
  const float* Whh_d = (const float*)d_in[19];
  const float* bih_d = (const float*)d_in[20];
  const float* bhh_d = (const float*)d_in[21];
  const float* W_ff  = (const float*)d_in[22];
  const float* b_ff  = (const float*)d_in[23];
  float* ws  = (float*)d_ws;
  float* out = (float*)d_out;

  k_prep<<<256, 512, 0, stream>>>(W_ah, Wih_e, Whh_e, W_d1, Wih_d, Whh_d, ws);
  k_attn<<<512, 128, 0, stream>>>(x, W_ai, b_ai, ws);
  k_encoder<<<256, 512, 0, stream>>>(x, b_ah, W_a, b_a, bih_e, bhh_e, ws);
  k_encw<<<1024, 256, 0, stream>>>(W_fc, ws);
  k_encproj<<<8192, 256, 0, stream>>>(W_d1, ws);
  k_decoder<<<256, 512, 0, stream>>>(y_h, b_d1, W_d2, b_d2, W_fc, b_fc,
                                     bih_d, bhh_d, W_ff, b_ff, ws, out);
}

// Round 3
// 21497.336 us; speedup vs baseline: 1.3855x; 1.3855x over previous
//
#include <hip/hip_runtime.h>
#include <hip/hip_bf16.h>
#include <hip/hip_fp16.h>

#define BB  512
#define TT  256
#define MM  81
#define HEE 256

// ---- workspace layout (float offsets) ----
#define OFF_W2AH   0          // half2[256 k2][256 j]  encoder p1 weights
#define OFF_WE8    65536      // uint4[169 k2][256 j]  encoder LSTM weights (4 gates x k-pair, fp16)
#define OFF_W2D1   238592     // half2[256 k2][256 j]  decoder p1 weights
#define OFF_WD8    304128     // uint4[129 k2][256 j]  decoder LSTM weights
#define OFF_ATTN   436224     // [512][81] attn_in
#define OFF_ENCW   477696     // [512][256] enc . W_fc[:256]
#define OFF_ENC    608768     // [512][256][256] input_encoded fp32
#define OFF_EPI    34163200   // half[512 b][256 t'][256 h] enc_proj
#define WS_FLOATS  50940416

__device__ __forceinline__ float frcp(float x) { return __builtin_amdgcn_rcpf(x); }
__device__ __forceinline__ float fsig(float x) { return frcp(1.f + __expf(-x)); }
__device__ __forceinline__ float ftanh(float x) { return 1.f - 2.f * frcp(__expf(2.f * x) + 1.f); }

// both-batch gate FMA: uv = (u[ke]b0, u[ke]b1, u[ko]b0, u[ko]b1)
__device__ __forceinline__ void gate_fma(const uint4& wu, const float4& uv, float4& g0, float4& g1) {
  const __half2* wh = reinterpret_cast<const __half2*>(&wu);
  float2 if0 = __half22float2(wh[0]);
  float2 go0 = __half22float2(wh[1]);
  float2 if1 = __half22float2(wh[2]);
  float2 go1 = __half22float2(wh[3]);
  g0.x = fmaf(if0.x, uv.x, fmaf(if1.x, uv.z, g0.x));
  g0.y = fmaf(if0.y, uv.x, fmaf(if1.y, uv.z, g0.y));
  g0.z = fmaf(go0.x, uv.x, fmaf(go1.x, uv.z, g0.z));
  g0.w = fmaf(go0.y, uv.x, fmaf(go1.y, uv.z, g0.w));
  g1.x = fmaf(if0.x, uv.y, fmaf(if1.x, uv.w, g1.x));
  g1.y = fmaf(if0.y, uv.y, fmaf(if1.y, uv.w, g1.y));
  g1.z = fmaf(go0.x, uv.y, fmaf(go1.x, uv.w, g1.z));
  g1.w = fmaf(go0.y, uv.y, fmaf(go1.y, uv.w, g1.w));
}

// ---------------- weight prep ----------------
__global__ void k_prep(const float* __restrict__ W_ah, const float* __restrict__ Wih_e,
                       const float* __restrict__ Whh_e, const float* __restrict__ W_d1,
                       const float* __restrict__ Wih_d, const float* __restrict__ Whh_d,
                       float* __restrict__ ws) {
  int idx = blockIdx.x * 512 + threadIdx.x;
  if (idx < 65536) {
    int k2 = idx >> 8, j = idx & 255;
    ((__half2*)(ws + OFF_W2AH))[idx] =
        __floats2half2_rn(W_ah[j * 512 + 2 * k2], W_ah[j * 512 + 2 * k2 + 1]);
    ((__half2*)(ws + OFF_W2D1))[idx] =
        __floats2half2_rn(W_d1[j * 768 + 2 * k2], W_d1[j * 768 + 2 * k2 + 1]);
  }
  if (idx < 43264) {  // 169*256
    int k2 = idx >> 8, j = idx & 255;
    auto we = [&](int g, int kk) -> float {
      if (kk < 81)  return Wih_e[(g * 256 + j) * 81 + kk];
      if (kk < 337) return Whh_e[(g * 256 + j) * 256 + (kk - 81)];
      return 0.f;
    };
    int ke = 2 * k2, ko = 2 * k2 + 1;
    union { __half2 h[4]; uint4 u; } w;
    w.h[0] = __floats2half2_rn(we(0, ke), we(1, ke));
    w.h[1] = __floats2half2_rn(we(2, ke), we(3, ke));
    w.h[2] = __floats2half2_rn(we(0, ko), we(1, ko));
    w.h[3] = __floats2half2_rn(we(2, ko), we(3, ko));
    ((uint4*)(ws + OFF_WE8))[idx] = w.u;
  }
  if (idx < 33024) {  // 129*256
    int k2 = idx >> 8, j = idx & 255;
    auto wd = [&](int g, int kk) -> float {
      if (kk == 0)  return Wih_d[g * 256 + j];
      if (kk < 257) return Whh_d[(g * 256 + j) * 256 + (kk - 1)];
      return 0.f;
    };
    int ke = 2 * k2, ko = 2 * k2 + 1;
    union { __half2 h[4]; uint4 u; } w;
    w.h[0] = __floats2half2_rn(wd(0, ke), wd(1, ke));
    w.h[1] = __floats2half2_rn(wd(2, ke), wd(3, ke));
    w.h[2] = __floats2half2_rn(wd(0, ko), wd(1, ko));
    w.h[3] = __floats2half2_rn(wd(2, ko), wd(3, ko));
    ((uint4*)(ws + OFF_WD8))[idx] = w.u;
  }
}

// ---------------- attn_in[b][m] ----------------
__global__ void k_attn(const float* __restrict__ x, const float* __restrict__ W_ai,
                       const float* __restrict__ b_ai, float* __restrict__ ws) {
  __shared__ float wai[256];
  const int b = blockIdx.x, tid = threadIdx.x;  // 128 threads
  wai[tid] = W_ai[tid];
  wai[128 + tid] = W_ai[128 + tid];
  __syncthreads();
  if (tid < MM) {
    float acc = b_ai[0];
    const float* xp = x + (size_t)b * TT * MM + tid;
    #pragma unroll 8
    for (int t = 0; t < TT; ++t) acc = fmaf(xp[t * MM], wai[t], acc);
    ws[OFF_ATTN + b * MM + tid] = acc;
  }
}

// ---------------- encoder: 1024 threads, 2 batch rows, 256 steps ----------------
__global__ __launch_bounds__(1024, 4) void k_encoder(
    const float* __restrict__ x, const float* __restrict__ b_ah,
    const float* __restrict__ W_a, const float* __restrict__ b_a,
    const float* __restrict__ bih_e, const float* __restrict__ bhh_e,
    float* __restrict__ ws) {
  __shared__ __align__(16) float arena[8192];   // pp(2048) / scp(1536) / gp(8192 as float4)
  __shared__ __align__(16) float hcat[1024];    // [h;c] packed addr = 2k+b
  __shared__ __align__(16) float ubuf[680];     // packed: (k>>1)*4+(k&1)*2+b, k in [0,338)
  __shared__ __align__(16) float hpb[512];      // hid_proj packed 2t+b
  __shared__ __align__(16) float wa2[256];
  const int tid = threadIdx.x;
  const int j = tid & 255, q = tid >> 8;
  const int b0 = blockIdx.x * 2, b1 = b0 + 1;
  const float* __restrict__ ench = ws + OFF_ENC;

  if (tid < 256) wa2[tid] = W_a[tid];
  hcat[tid] = 0.f;
  if (tid < 680) ubuf[tid] = 0.f;
  // per-thread constants
  float bahr = 0.f; float4 bias4 = {0, 0, 0, 0};
  if (tid < 512) {
    bahr = b_ah[j];
    bias4.x = bih_e[j] + bhh_e[j];
    bias4.y = bih_e[256 + j] + bhh_e[256 + j];
    bias4.z = bih_e[512 + j] + bhh_e[512 + j];
    bias4.w = bih_e[768 + j] + bhh_e[768 + j];
  }
  float ai0 = 0.f, ai1 = 0.f;
  {
    int m = tid & 127;
    if (m < MM) {
      ai0 = ws[OFF_ATTN + b0 * MM + m];
      ai1 = ws[OFF_ATTN + b1 * MM + m];
    }
  }
  const float bav = b_a[0];
  float xc0 = 0.f, xc1 = 0.f;
  if (tid < 128) {
    int bb = (tid >= 64) ? b1 : b0;
    int lane = tid & 63;
    xc0 = x[((size_t)bb * TT) * MM + lane];
    xc1 = (lane < 17) ? x[((size_t)bb * TT) * MM + 64 + lane] : 0.f;
  }
  const __half2* __restrict__ Wah2 = (const __half2*)(ws + OFF_W2AH);
  const uint4* __restrict__ We8 = (const uint4*)(ws + OFF_WE8);
  float4* __restrict__ arena4 = (float4*)arena;
  __syncthreads();

  for (int t = 0; t < TT; ++t) {
    // ---- p1: hid_proj partials (4-way k2 split) ----
    {
      float a0 = 0.f, a1 = 0.f;
      const int kb = q * 64;
      #pragma unroll 8
      for (int i = 0; i < 64; ++i) {
        int k2 = kb + i;
        float2 wf = __half22float2(Wah2[k2 * 256 + j]);
        float4 hv = *(const float4*)&hcat[k2 * 4];
        a0 = fmaf(wf.x, hv.x, fmaf(wf.y, hv.z, a0));
        a1 = fmaf(wf.x, hv.y, fmaf(wf.y, hv.w, a1));
      }
      arena[(q * 256 + j) * 2 + 0] = a0;
      arena[(q * 256 + j) * 2 + 1] = a1;
    }
    __syncthreads();
    if (tid < 512) {
      int b = tid >> 8, h = tid & 255;
      float v = arena[(0 * 256 + h) * 2 + b] + arena[(1 * 256 + h) * 2 + b] +
                arena[(2 * 256 + h) * 2 + b] + arena[(3 * 256 + h) * 2 + b] + bahr;
      hpb[2 * h + b] = v;
    }
    __syncthreads();
    // ---- p2: score[m] partials over 8 t-slices ----
    {
      int m = tid & 127, tq = tid >> 7;
      if (m < MM) {
        float e0 = 0.f, e1 = 0.f;
        #pragma unroll 8
        for (int i = tq * 16; i < tq * 16 + 16; ++i) {
          float4 hv = *(const float4*)&hpb[i * 4];
          float2 wv = *(const float2*)&wa2[i * 2];
          e0 += ftanh(hv.x + ai0) * wv.x + ftanh(hv.z + ai0) * wv.y;
          e1 += ftanh(hv.y + ai1) * wv.x + ftanh(hv.w + ai1) * wv.y;
        }
        arena[(tq * 2 + 0) * 96 + m] = e0;
        arena[(tq * 2 + 1) * 96 + m] = e1;
      }
    }
    __syncthreads();
    // ---- p3: softmax over m + wi (waves 0,1) ----
    if (tid < 128) {
      int wv_id = tid >> 6, lane = tid & 63;
      float v0 = bav, v1 = (lane < 17) ? bav : -1e30f;
      #pragma unroll
      for (int tq = 0; tq < 8; ++tq) {
        v0 += arena[(tq * 2 + wv_id) * 96 + lane];
        if (lane < 17) v1 += arena[(tq * 2 + wv_id) * 96 + 64 + lane];
      }
      float mx = fmaxf(v0, v1);
      #pragma unroll
      for (int d = 1; d < 64; d <<= 1) mx = fmaxf(mx, __shfl_xor(mx, d));
      float e0 = __expf(v0 - mx);
      float e1 = (lane < 17) ? __expf(v1 - mx) : 0.f;
      float sm = e0 + e1;
      #pragma unroll
      for (int d = 1; d < 64; d <<= 1) sm += __shfl_xor(sm, d);
      float inv = frcp(sm);
      float w0 = e0 * inv * xc0;
      float w1 = e1 * inv * xc1;
      int m0 = lane, m1 = 64 + lane;
      ubuf[(m0 >> 1) * 4 + (m0 & 1) * 2 + wv_id] = w0;
      if (lane < 17) ubuf[(m1 >> 1) * 4 + (m1 & 1) * 2 + wv_id] = w1;
      if (t < 255) {
        int bb = wv_id ? b1 : b0;
        xc0 = x[((size_t)bb * TT + t + 1) * MM + lane];
        xc1 = (lane < 17) ? x[((size_t)bb * TT + t + 1) * MM + 64 + lane] : 0.f;
      }
    }
    __syncthreads();
    // ---- p4: LSTM gate partials (4-way k2 split over 169) ----
    {
      const int kA = (q == 0) ? 0 : (q == 1) ? 43 : (q == 2) ? 86 : 128;
      const int kB = (q == 0) ? 43 : (q == 1) ? 86 : (q == 2) ? 128 : 169;
      float4 g0 = {0, 0, 0, 0}, g1 = {0, 0, 0, 0};
      #pragma unroll 4
      for (int k2 = kA; k2 < kB; ++k2) {
        uint4 wu = We8[k2 * 256 + j];
        float4 uv = *(const float4*)&ubuf[k2 * 4];
        gate_fma(wu, uv, g0, g1);
      }
      arena4[(q * 2 + 0) * 256 + j] = g0;
      arena4[(q * 2 + 1) * 256 + j] = g1;
    }
    __syncthreads();
    // ---- p4 reduce + state update ----
    if (tid < 512) {
      int b = tid >> 8, jj = tid & 255;
      float4 s0 = arena4[(0 * 2 + b) * 256 + jj];
      float4 s1 = arena4[(1 * 2 + b) * 256 + jj];
      float4 s2 = arena4[(2 * 2 + b) * 256 + jj];
      float4 s3 = arena4[(3 * 2 + b) * 256 + jj];
      float gi = s0.x + s1.x + s2.x + s3.x + bias4.x;
      float gf = s0.y + s1.y + s2.y + s3.y + bias4.y;
      float gg = s0.z + s1.z + s2.z + s3.z + bias4.z;
      float go = s0.w + s1.w + s2.w + s3.w + bias4.w;
      float cold = hcat[2 * (256 + jj) + b];
      float c = fsig(gf) * cold + fsig(gi) * ftanh(gg);
      float h = fsig(go) * ftanh(c);
      hcat[2 * jj + b] = h;
      hcat[2 * (256 + jj) + b] = c;
      int us = 81 + jj;
      ubuf[(us >> 1) * 4 + (us & 1) * 2 + b] = h;
      ws[OFF_ENC + (((size_t)(b ? b1 : b0) * TT + t) * HEE + jj)] = h;
    }
    __syncthreads();
  }
  (void)ench;
}

// ---------------- encW[b][t] = enc[b,t,:] . W_fc[:256] ----------------
__global__ __launch_bounds__(256) void k_encw(const float* __restrict__ W_fc, float* __restrict__ ws) {
  const float* __restrict__ enc = ws + OFF_ENC;
  const int wv = threadIdx.x >> 6, lane = threadIdx.x & 63;
  float4 wfc = reinterpret_cast<const float4*>(W_fc)[lane];
  for (int r = blockIdx.x * 4 + wv; r < BB * TT; r += 4096) {
    float4 e = reinterpret_cast<const float4*>(enc + (size_t)r * HEE)[lane];
    float d = e.x * wfc.x + e.y * wfc.y + e.z * wfc.z + e.w * wfc.w;
    #pragma unroll
    for (int dd = 1; dd < 64; dd <<= 1) d += __shfl_xor(d, dd);
    if (lane == 0) ws[OFF_ENCW + r] = d;
  }
}

// ---------------- enc_proj fp16: epH[b][t'][h] ----------------
__global__ __launch_bounds__(256) void k_encproj(const float* __restrict__ W_d1, float* __restrict__ ws) {
  __shared__ __align__(16) float le[16][256];
  const int tid = threadIdx.x;
  const int b = blockIdx.x >> 4;
  const int t0 = (blockIdx.x & 15) * 16;
  const float* __restrict__ enc = ws + OFF_ENC;
  __half* __restrict__ epH = (__half*)(ws + OFF_EPI);
  #pragma unroll
  for (int rr = 0; rr < 16; ++rr)
    le[rr][tid] = enc[((size_t)b * TT + (t0 + rr)) * HEE + tid];
  __syncthreads();
  const float4* wrow = (const float4*)(W_d1 + (size_t)tid * 768 + 512);
  float acc[16];
  #pragma unroll
  for (int r = 0; r < 16; ++r) acc[r] = 0.f;
  for (int e4 = 0; e4 < 64; ++e4) {
    float4 w = wrow[e4];
    #pragma unroll
    for (int r = 0; r < 16; ++r) {
      float4 ev = *(const float4*)&le[r][e4 * 4];
      acc[r] += ev.x * w.x + ev.y * w.y + ev.z * w.z + ev.w * w.w;
    }
  }
  #pragma unroll
  for (int rr = 0; rr < 16; ++rr)
    epH[((size_t)b * TT + (t0 + rr)) * HEE + tid] = __float2half(acc[rr]);
}

// ---------------- decoder: 1024 threads, 2 batch rows, 255 steps ----------------
__global__ __launch_bounds__(1024, 4) void k_decoder(
    const float* __restrict__ y_history, const float* __restrict__ b_d1,
    const float* __restrict__ W_d2, const float* __restrict__ b_d2,
    const float* __restrict__ W_fc, const float* __restrict__ b_fc,
    const float* __restrict__ bih_d, const float* __restrict__ bhh_d,
    const float* __restrict__ W_ff, const float* __restrict__ b_ff,
    float* __restrict__ ws, float* __restrict__ out) {
  __shared__ __align__(16) ushort epL[65536];   // b0 enc_proj, swizzled, 128 KB
  __shared__ __align__(16) float arena[4096];   // pp / qp / gp / cp (16 KB)
  __shared__ __align__(16) float hcat[1024];    // [h;c] packed 2k+b
  __shared__ __align__(16) float ub2[2][260];   // per-batch LSTM input: [0]=y, [1+j]=h
  __shared__ __align__(16) float ddp2[512];     // d packed 2h+b
  __shared__ __align__(16) ushort w2h[256];     // W_d2 fp16
  __shared__ __align__(16) float ybuf[512];     // y*wfcy+bfc, 2s+b
  __shared__ __align__(16) float awls[512];     // last-step aw, 2t+b
  __shared__ float red[3][8];
  const int tid = threadIdx.x;
  const int tp = tid & 255, q = tid >> 8;
  const int lane = tid & 63, wvid = tid >> 6;
  const int b0 = blockIdx.x * 2, b1 = b0 + 1;

  const float wfcy = W_fc[256], bfc = b_fc[0], bd2v = b_d2[0];
  hcat[tid] = 0.f;
  if (tid < 520) ((float*)ub2)[tid] = 0.f;
  if (tid < 256) w2h[tid] = __half_as_ushort(__float2half(W_d2[tid]));
  if (tid < 510) {
    int s = tid >> 1, b = tid & 1;
    ybuf[tid] = y_history[(size_t)(b ? b1 : b0) * 255 + s] * wfcy + bfc;
  }
  float bd1r = 0.f; float4 biasd = {0, 0, 0, 0};
  if (tid < 512) {
    bd1r = b_d1[tp];
    biasd.x = bih_d[tp] + bhh_d[tp];
    biasd.y = bih_d[256 + tp] + bhh_d[256 + tp];
    biasd.z = bih_d[512 + tp] + bhh_d[512 + tp];
    biasd.w = bih_d[768 + tp] + bhh_d[768 + tp];
  }
  float ewr = 0.f;
  if (q < 2) ewr = ws[OFF_ENCW + (size_t)(q ? b1 : b0) * 256 + tp];

  // ---- load enc_proj: b0 -> swizzled LDS, b1 -> regs ----
  const uint4* __restrict__ epg = (const uint4*)(ws + OFF_EPI);
  {
    const uint4* src = epg + (size_t)b0 * 8192;
    uint4* dst = (uint4*)epL;
    #pragma unroll
    for (int k = 0; k < 8; ++k) {
      int g = k * 1024 + tid;
      int t = g >> 5, c = g & 31;
      dst[(g & ~31) | (c ^ (t & 31))] = src[g];
    }
  }
  uint4 epr[8];
  {
    const uint4* s1 = epg + (size_t)b1 * 8192 + tp * 32 + q * 8;
    #pragma unroll
    for (int k = 0; k < 8; ++k) epr[k] = s1[k];
  }

  const __half2* __restrict__ Wd2h = (const __half2*)(ws + OFF_W2D1);
  const uint4* __restrict__ Wd8 = (const uint4*)(ws + OFF_WD8);
  float4* __restrict__ arena4 = (float4*)arena;
  const uint4* __restrict__ ep16 = (const uint4*)epL;
  __syncthreads();

  for (int s = 0; s < 255; ++s) {
    // ---- p1: d = [h;c].W_d1hc^T partials ----
    {
      float a0 = 0.f, a1 = 0.f;
      const int kb = q * 64;
      #pragma unroll 8
      for (int i = 0; i < 64; ++i) {
        int k2 = kb + i;
        float2 wf = __half22float2(Wd2h[k2 * 256 + tp]);
        float4 hv = *(const float4*)&hcat[k2 * 4];
        a0 = fmaf(wf.x, hv.x, fmaf(wf.y, hv.z, a0));
        a1 = fmaf(wf.x, hv.y, fmaf(wf.y, hv.w, a1));
      }
      arena[(q * 256 + tp) * 2 + 0] = a0;
      arena[(q * 256 + tp) * 2 + 1] = a1;
    }
    __syncthreads();
    if (tid < 512) {
      int b = tid >> 8, h = tid & 255;
      float d = arena[(0 * 256 + h) * 2 + b] + arena[(1 * 256 + h) * 2 + b] +
                arena[(2 * 256 + h) * 2 + b] + arena[(3 * 256 + h) * 2 + b] + bd1r;
      ddp2[2 * h + b] = d;
    }
    __syncthreads();
    // ---- p2: score partials (b0 from LDS, b1 from regs) ----
    {
      float q0 = 0.f, q1 = 0.f;
      const int rowbase = tp * 32, sw = tp & 31;
      #pragma unroll
      for (int k = 0; k < 8; ++k) {
        uint4 e0u = ep16[rowbase + ((q * 8 + k) ^ sw)];
        uint4 e1u = epr[k];
        const int h8 = q * 64 + k * 8;
        uint4 w2u = *(const uint4*)&w2h[h8];
        const __half2* e0h = (const __half2*)&e0u;
        const __half2* e1h = (const __half2*)&e1u;
        const __half2* w2p = (const __half2*)&w2u;
        #pragma unroll
        for (int jj = 0; jj < 4; ++jj) {
          float2 ea = __half22float2(e0h[jj]);
          float2 eb = __half22float2(e1h[jj]);
          float2 wf = __half22float2(w2p[jj]);
          float4 dv = *(const float4*)&ddp2[2 * (h8 + 2 * jj)];
          q0 += wf.x * ftanh(ea.x + dv.x) + wf.y * ftanh(ea.y + dv.z);
          q1 += wf.x * ftanh(eb.x + dv.y) + wf.y * ftanh(eb.y + dv.w);
        }
      }
      arena[(q * 256 + tp) * 2 + 0] = q0;
      arena[(q * 256 + tp) * 2 + 1] = q1;
    }
    __syncthreads();
    // ---- p3: softmax over t' (q<2 active, b=q) ----
    float vsc = 0.f, esc = 0.f;
    if (q < 2) {
      vsc = arena[(0 * 256 + tp) * 2 + q] + arena[(1 * 256 + tp) * 2 + q] +
            arena[(2 * 256 + tp) * 2 + q] + arena[(3 * 256 + tp) * 2 + q] + bd2v;
      float mx = vsc;
      #pragma unroll
      for (int d = 1; d < 64; d <<= 1) mx = fmaxf(mx, __shfl_xor(mx, d));
      if (lane == 0) red[0][wvid] = mx;
    }
    __syncthreads();
    if (q < 2) {
      float mx = fmaxf(fmaxf(red[0][q * 4 + 0], red[0][q * 4 + 1]),
                       fmaxf(red[0][q * 4 + 2], red[0][q * 4 + 3]));
      esc = __expf(vsc - mx);
      float den = esc, num = esc * ewr;
      #pragma unroll
      for (int d = 1; d < 64; d <<= 1) { den += __shfl_xor(den, d); num += __shfl_xor(num, d); }
      if (lane == 0) { red[1][wvid] = den; red[2][wvid] = num; }
    }
    __syncthreads();
    if (q < 2) {
      float den = red[1][q * 4 + 0] + red[1][q * 4 + 1] + red[1][q * 4 + 2] + red[1][q * 4 + 3];
      float num = red[2][q * 4 + 0] + red[2][q * 4 + 1] + red[2][q * 4 + 2] + red[2][q * 4 + 3];
      float inv = frcp(den);
      if (tp == 0) ub2[q][0] = num * inv + ybuf[2 * s + q];
      if (s == 254) awls[2 * tp + q] = esc * inv;
    }
    __syncthreads();
    // ---- p5: decoder LSTM gate partials (per-batch, 2-way k2 split) ----
    {
      const int b = q >> 1, half = q & 1;
      const float* ub = ub2[b];
      const int kA = half ? 65 : 0, kB = half ? 129 : 65;
      float4 g = {0, 0, 0, 0};
      #pragma unroll 4
      for (int k2 = kA; k2 < kB; ++k2) {
        uint4 wu = Wd8[k2 * 256 + tp];
        const __half2* wh = (const __half2*)&wu;
        float2 ife = __half22float2(wh[0]);
        float2 goe = __half22float2(wh[1]);
        float2 ifo = __half22float2(wh[2]);
        float2 goo = __half22float2(wh[3]);
        float2 uv = *(const float2*)&ub[2 * k2];
        g.x = fmaf(ife.x, uv.x, fmaf(ifo.x, uv.y, g.x));
        g.y = fmaf(ife.y, uv.x, fmaf(ifo.y, uv.y, g.y));
        g.z = fmaf(goe.x, uv.x, fmaf(goo.x, uv.y, g.z));
        g.w = fmaf(goe.y, uv.x, fmaf(goo.y, uv.y, g.w));
      }
      arena4[q * 256 + tp] = g;
    }
    __syncthreads();
    if (tid < 512) {
      int b = tid >> 8, jj = tid & 255;
      float4 ga = arena4[(b * 2 + 0) * 256 + jj];
      float4 gb = arena4[(b * 2 + 1) * 256 + jj];
      float gi = ga.x + gb.x + biasd.x, gf = ga.y + gb.y + biasd.y;
      float gg = ga.z + gb.z + biasd.z, go = ga.w + gb.w + biasd.w;
      float cold = hcat[2 * (256 + jj) + b];
      float c = fsig(gf) * cold + fsig(gi) * ftanh(gg);
      float h = fsig(go) * ftanh(c);
      hcat[2 * jj + b] = h;
      hcat[2 * (256 + jj) + b] = c;
      ub2[b][1 + jj] = h;
    }
    __syncthreads();
  }

  // ---- final: ctx with last-step aw + output ----
  {
    float c0 = 0.f, c1 = 0.f;
    const float* __restrict__ e0p = ws + OFF_ENC + (size_t)b0 * TT * HEE;
    const float* __restrict__ e1p = ws + OFF_ENC + (size_t)b1 * TT * HEE;
    for (int t = q * 64; t < q * 64 + 64; ++t) {
      float2 aw = *(const float2*)&awls[2 * t];
      c0 = fmaf(aw.x, e0p[(size_t)t * HEE + tp], c0);
      c1 = fmaf(aw.y, e1p[(size_t)t * HEE + tp], c1);
    }
    arena[(q * 256 + tp) * 2 + 0] = c0;
    arena[(q * 256 + tp) * 2 + 1] = c1;
  }
  __syncthreads();
  if (tid < 512) {
    int b = tid >> 8, h = tid & 255;
    float ctx = arena[(0 * 256 + h) * 2 + b] + arena[(1 * 256 + h) * 2 + b] +
                arena[(2 * 256 + h) * 2 + b] + arena[(3 * 256 + h) * 2 + b];
    float hfin = hcat[2 * h + b];
    float p = hfin * W_ff[h] + ctx * W_ff[256 + h];
    #pragma unroll
    for (int d = 1; d < 64; d <<= 1) p += __shfl_xor(p, d);
    if (lane == 0) red[0][wvid] = p;
  }
  __syncthreads();
  if (tid == 0)   out[b0] = red[0][0] + red[0][1] + red[0][2] + red[0][3] + b_ff[0];
  if (tid == 256) out[b1] = red[0][4] + red[0][5] + red[0][6] + red[0][7] + b_ff[0];
}

extern "C" void kernel_launch(void* const* d_in, const int* in_sizes, int n_in,
                              void* d_out, int out_size, void* d_ws, size_t ws_size,
                              hipStream_t stream) {
  if (ws_size < (size_t)WS_FLOATS * sizeof(float)) return;
  const float* x     = (const float*)d_in[0];
  const float* y_h   = (const float*)d_in[1];
  const float* W_ah  = (const float*)d_in[2];
  const float* b_ah  = (const float*)d_in[3];
  const float* W_ai  = (const float*)d_in[4];
  const float* b_ai  = (const float*)d_in[5];
  const float* W_a   = (const float*)d_in[6];
  const float* b_a   = (const float*)d_in[7];
  const float* Wih_e = (const float*)d_in[8];
  const float* Whh_e = (const float*)d_in[9];
  const float* bih_e = (const float*)d_in[10];
  const float* bhh_e = (const float*)d_in[11];
  const float* W_d1  = (const float*)d_in[12];
  const float* b_d1  = (const float*)d_in[13];
  const float* W_d2  = (const float*)d_in[14];
  const float* b_d2  = (const float*)d_in[15];
  const float* W_fc  = (const float*)d_in[16];
  const float* b_fc  = (const float*)d_in[17];
  const float* Wih_d = (const float*)d_in[18];
  const float* Whh_d = (const float*)d_in[19];
  const float* bih_d = (const float*)d_in[20];
  const float* bhh_d = (const float*)d_in[21];
  const float* W_ff  = (const float*)d_in[22];
  const float* b_ff  = (const float*)d_in[23];
  float* ws  = (float*)d_ws;
  float* out = (float*)d_out;

  k_prep<<<256, 512, 0, stream>>>(W_ah, Wih_e, Whh_e, W_d1, Wih_d, Whh_d, ws);
  k_attn<<<512, 128, 0, stream>>>(x, W_ai, b_ai, ws);
  k_encoder<<<256, 1024, 0, stream>>>(x, b_ah, W_a, b_a, bih_e, bhh_e, ws);
  k_encw<<<1024, 256, 0, stream>>>(W_fc, ws);
  k_encproj<<<8192, 256, 0, stream>>>(W_d1, ws);
  k_decoder<<<256, 1024, 0, stream>>>(y_h, b_d1, W_d2, b_d2, W_fc, b_fc,
                                      bih_d, bhh_d, W_ff, b_ff, ws, out);
}

// Round 4
// 21472.830 us; speedup vs baseline: 1.3871x; 1.0011x over previous
//
#include <hip/hip_runtime.h>
#include <hip/hip_bf16.h>
#include <hip/hip_fp16.h>

#define BB  512
#define TT  256
#define MM  81
#define HEE 256

// ---- workspace layout (float offsets) ----
#define OFF_W2AH   0          // half2[256 k2][256 j]  encoder p1 weights
#define OFF_WE8    65536      // uint4[169 k2][256 j]  encoder LSTM weights (4 gates x k-pair, fp16)
#define OFF_W2D1   238592     // half2[256 k2][256 j]  decoder p1 weights
#define OFF_WD8    304128     // uint4[129 k2][256 j]  decoder LSTM weights
#define OFF_ATTN   436224     // [512][81] attn_in
#define OFF_ENCW   477696     // [512][256] enc . W_fc[:256]
#define OFF_ENC    608768     // [512][256][256] input_encoded fp32
#define OFF_EPI    34163200   // half[512 b][256 t'][256 h] enc_proj
#define WS_FLOATS  50940416

__device__ __forceinline__ float frcp(float x) { return __builtin_amdgcn_rcpf(x); }
__device__ __forceinline__ float fsig(float x) { return frcp(1.f + __expf(-x)); }
__device__ __forceinline__ float ftanh(float x) { return 1.f - 2.f * frcp(__expf(2.f * x) + 1.f); }

// both-batch gate FMA: uv = (u[ke]b0, u[ke]b1, u[ko]b0, u[ko]b1)
__device__ __forceinline__ void gate_fma(const uint4& wu, const float4& uv, float4& g0, float4& g1) {
  const __half2* wh = reinterpret_cast<const __half2*>(&wu);
  float2 if0 = __half22float2(wh[0]);
  float2 go0 = __half22float2(wh[1]);
  float2 if1 = __half22float2(wh[2]);
  float2 go1 = __half22float2(wh[3]);
  g0.x = fmaf(if0.x, uv.x, fmaf(if1.x, uv.z, g0.x));
  g0.y = fmaf(if0.y, uv.x, fmaf(if1.y, uv.z, g0.y));
  g0.z = fmaf(go0.x, uv.x, fmaf(go1.x, uv.z, g0.z));
  g0.w = fmaf(go0.y, uv.x, fmaf(go1.y, uv.z, g0.w));
  g1.x = fmaf(if0.x, uv.y, fmaf(if1.x, uv.w, g1.x));
  g1.y = fmaf(if0.y, uv.y, fmaf(if1.y, uv.w, g1.y));
  g1.z = fmaf(go0.x, uv.y, fmaf(go1.x, uv.w, g1.z));
  g1.w = fmaf(go0.y, uv.y, fmaf(go1.y, uv.w, g1.w));
}

// ---------------- weight prep ----------------
__global__ void k_prep(const float* __restrict__ W_ah, const float* __restrict__ Wih_e,
                       const float* __restrict__ Whh_e, const float* __restrict__ W_d1,
                       const float* __restrict__ Wih_d, const float* __restrict__ Whh_d,
                       float* __restrict__ ws) {
  int idx = blockIdx.x * 512 + threadIdx.x;
  if (idx < 65536) {
    int k2 = idx >> 8, j = idx & 255;
    ((__half2*)(ws + OFF_W2AH))[idx] =
        __floats2half2_rn(W_ah[j * 512 + 2 * k2], W_ah[j * 512 + 2 * k2 + 1]);
    ((__half2*)(ws + OFF_W2D1))[idx] =
        __floats2half2_rn(W_d1[j * 768 + 2 * k2], W_d1[j * 768 + 2 * k2 + 1]);
  }
  if (idx < 43264) {  // 169*256
    int k2 = idx >> 8, j = idx & 255;
    auto we = [&](int g, int kk) -> float {
      if (kk < 81)  return Wih_e[(g * 256 + j) * 81 + kk];
      if (kk < 337) return Whh_e[(g * 256 + j) * 256 + (kk - 81)];
      return 0.f;
    };
    int ke = 2 * k2, ko = 2 * k2 + 1;
    union { __half2 h[4]; uint4 u; } w;
    w.h[0] = __floats2half2_rn(we(0, ke), we(1, ke));
    w.h[1] = __floats2half2_rn(we(2, ke), we(3, ke));
    w.h[2] = __floats2half2_rn(we(0, ko), we(1, ko));
    w.h[3] = __floats2half2_rn(we(2, ko), we(3, ko));
    ((uint4*)(ws + OFF_WE8))[idx] = w.u;
  }
  if (idx < 33024) {  // 129*256
    int k2 = idx >> 8, j = idx & 255;
    auto wd = [&](int g, int kk) -> float {
      if (kk == 0)  return Wih_d[g * 256 + j];
      if (kk < 257) return Whh_d[(g * 256 + j) * 256 + (kk - 1)];
      return 0.f;
    };
    int ke = 2 * k2, ko = 2 * k2 + 1;
    union { __half2 h[4]; uint4 u; } w;
    w.h[0] = __floats2half2_rn(wd(0, ke), wd(1, ke));
    w.h[1] = __floats2half2_rn(wd(2, ke), wd(3, ke));
    w.h[2] = __floats2half2_rn(wd(0, ko), wd(1, ko));
    w.h[3] = __floats2half2_rn(wd(2, ko), wd(3, ko));
    ((uint4*)(ws + OFF_WD8))[idx] = w.u;
  }
}

// ---------------- attn_in[b][m] ----------------
__global__ void k_attn(const float* __restrict__ x, const float* __restrict__ W_ai,
                       const float* __restrict__ b_ai, float* __restrict__ ws) {
  __shared__ float wai[256];
  const int b = blockIdx.x, tid = threadIdx.x;  // 128 threads
  wai[tid] = W_ai[tid];
  wai[128 + tid] = W_ai[128 + tid];
  __syncthreads();
  if (tid < MM) {
    float acc = b_ai[0];
    const float* xp = x + (size_t)b * TT * MM + tid;
    #pragma unroll 8
    for (int t = 0; t < TT; ++t) acc = fmaf(xp[t * MM], wai[t], acc);
    ws[OFF_ATTN + b * MM + tid] = acc;
  }
}

// ---------------- encoder: 1024 threads, 2 batch rows, 256 steps ----------------
__global__ __launch_bounds__(1024, 2) void k_encoder(
    const float* __restrict__ x, const float* __restrict__ b_ah,
    const float* __restrict__ W_a, const float* __restrict__ b_a,
    const float* __restrict__ bih_e, const float* __restrict__ bhh_e,
    float* __restrict__ ws) {
  __shared__ __align__(16) float arena[8192];   // pp(2048) / scp(1536) / gp(8192 as float4)
  __shared__ __align__(16) float hcat[1024];    // [h;c] packed addr = 2k + b
  __shared__ __align__(16) float ubuf[680];     // packed: (k>>1)*4+(k&1)*2+b, k in [0,338)
  __shared__ __align__(16) float hpb[512];      // hid_proj packed 2t+b
  __shared__ __align__(16) float wa2[256];
  const int tid = threadIdx.x;
  const int j = tid & 255, q = tid >> 8;
  const int b0 = blockIdx.x * 2, b1 = b0 + 1;

  if (tid < 256) wa2[tid] = W_a[tid];
  hcat[tid] = 0.f;
  if (tid < 680) ubuf[tid] = 0.f;
  // per-thread constants
  float bahr = 0.f; float4 bias4 = {0, 0, 0, 0};
  if (tid < 512) {
    bahr = b_ah[j];
    bias4.x = bih_e[j] + bhh_e[j];
    bias4.y = bih_e[256 + j] + bhh_e[256 + j];
    bias4.z = bih_e[512 + j] + bhh_e[512 + j];
    bias4.w = bih_e[768 + j] + bhh_e[768 + j];
  }
  float ai0 = 0.f, ai1 = 0.f;
  {
    int m = tid & 127;
    if (m < MM) {
      ai0 = ws[OFF_ATTN + b0 * MM + m];
      ai1 = ws[OFF_ATTN + b1 * MM + m];
    }
  }
  const float bav = b_a[0];
  float xc0 = 0.f, xc1 = 0.f;
  if (tid < 128) {
    int bb = (tid >= 64) ? b1 : b0;
    int lane = tid & 63;
    xc0 = x[((size_t)bb * TT) * MM + lane];
    xc1 = (lane < 17) ? x[((size_t)bb * TT) * MM + 64 + lane] : 0.f;
  }
  const __half2* __restrict__ Wah2 = (const __half2*)(ws + OFF_W2AH);
  const uint4* __restrict__ We8 = (const uint4*)(ws + OFF_WE8);
  float4* __restrict__ arena4 = (float4*)arena;
  __syncthreads();

  for (int t = 0; t < TT; ++t) {
    // ---- p1: hid_proj partials (4-way k2 split) ----
    {
      float a0 = 0.f, a1 = 0.f;
      const int kb = q * 64;
      #pragma unroll 8
      for (int i = 0; i < 64; ++i) {
        int k2 = kb + i;
        float2 wf = __half22float2(Wah2[k2 * 256 + j]);
        float4 hv = *(const float4*)&hcat[k2 * 4];
        a0 = fmaf(wf.x, hv.x, fmaf(wf.y, hv.z, a0));
        a1 = fmaf(wf.x, hv.y, fmaf(wf.y, hv.w, a1));
      }
      arena[(q * 256 + j) * 2 + 0] = a0;
      arena[(q * 256 + j) * 2 + 1] = a1;
    }
    __syncthreads();
    if (tid < 512) {
      int b = tid >> 8, h = tid & 255;
      float v = arena[(0 * 256 + h) * 2 + b] + arena[(1 * 256 + h) * 2 + b] +
                arena[(2 * 256 + h) * 2 + b] + arena[(3 * 256 + h) * 2 + b] + bahr;
      hpb[2 * h + b] = v;
    }
    __syncthreads();
    // ---- p2: score[m] partials over 8 t-slices ----
    {
      int m = tid & 127, tq = tid >> 7;
      if (m < MM) {
        float e0 = 0.f, e1 = 0.f;
        #pragma unroll 8
        for (int i = tq * 16; i < tq * 16 + 16; ++i) {
          float4 hv = *(const float4*)&hpb[i * 4];
          float2 wv = *(const float2*)&wa2[i * 2];
          e0 += ftanh(hv.x + ai0) * wv.x + ftanh(hv.z + ai0) * wv.y;
          e1 += ftanh(hv.y + ai1) * wv.x + ftanh(hv.w + ai1) * wv.y;
        }
        arena[(tq * 2 + 0) * 96 + m] = e0;
        arena[(tq * 2 + 1) * 96 + m] = e1;
      }
    }
    __syncthreads();
    // ---- p3: softmax over m + wi (waves 0,1) ----
    if (tid < 128) {
      int wv_id = tid >> 6, lane = tid & 63;
      float v0 = bav, v1 = (lane < 17) ? bav : -1e30f;
      #pragma unroll
      for (int tq = 0; tq < 8; ++tq) {
        v0 += arena[(tq * 2 + wv_id) * 96 + lane];
        if (lane < 17) v1 += arena[(tq * 2 + wv_id) * 96 + 64 + lane];
      }
      float mx = fmaxf(v0, v1);
      #pragma unroll
      for (int d = 1; d < 64; d <<= 1) mx = fmaxf(mx, __shfl_xor(mx, d));
      float e0 = __expf(v0 - mx);
      float e1 = (lane < 17) ? __expf(v1 - mx) : 0.f;
      float sm = e0 + e1;
      #pragma unroll
      for (int d = 1; d < 64; d <<= 1) sm += __shfl_xor(sm, d);
      float inv = frcp(sm);
      float w0 = e0 * inv * xc0;
      float w1 = e1 * inv * xc1;
      int m0 = lane, m1 = 64 + lane;
      ubuf[(m0 >> 1) * 4 + (m0 & 1) * 2 + wv_id] = w0;
      if (lane < 17) ubuf[(m1 >> 1) * 4 + (m1 & 1) * 2 + wv_id] = w1;
      if (t < 255) {
        int bb = wv_id ? b1 : b0;
        xc0 = x[((size_t)bb * TT + t + 1) * MM + lane];
        xc1 = (lane < 17) ? x[((size_t)bb * TT + t + 1) * MM + 64 + lane] : 0.f;
      }
    }
    __syncthreads();
    // ---- p4: LSTM gate partials (4-way k2 split over 169) ----
    {
      const int kA = (q == 0) ? 0 : (q == 1) ? 43 : (q == 2) ? 86 : 128;
      const int kB = (q == 0) ? 43 : (q == 1) ? 86 : (q == 2) ? 128 : 169;
      float4 g0 = {0, 0, 0, 0}, g1 = {0, 0, 0, 0};
      #pragma unroll 4
      for (int k2 = kA; k2 < kB; ++k2) {
        uint4 wu = We8[k2 * 256 + j];
        float4 uv = *(const float4*)&ubuf[k2 * 4];
        gate_fma(wu, uv, g0, g1);
      }
      arena4[(q * 2 + 0) * 256 + j] = g0;
      arena4[(q * 2 + 1) * 256 + j] = g1;
    }
    __syncthreads();
    // ---- p4 reduce + state update ----
    if (tid < 512) {
      int b = tid >> 8, jj = tid & 255;
      float4 s0 = arena4[(0 * 2 + b) * 256 + jj];
      float4 s1 = arena4[(1 * 2 + b) * 256 + jj];
      float4 s2 = arena4[(2 * 2 + b) * 256 + jj];
      float4 s3 = arena4[(3 * 2 + b) * 256 + jj];
      float gi = s0.x + s1.x + s2.x + s3.x + bias4.x;
      float gf = s0.y + s1.y + s2.y + s3.y + bias4.y;
      float gg = s0.z + s1.z + s2.z + s3.z + bias4.z;
      float go = s0.w + s1.w + s2.w + s3.w + bias4.w;
      float cold = hcat[2 * (256 + jj) + b];
      float c = fsig(gf) * cold + fsig(gi) * ftanh(gg);
      float h = fsig(go) * ftanh(c);
      hcat[2 * jj + b] = h;
      hcat[2 * (256 + jj) + b] = c;
      int us = 81 + jj;
      ubuf[(us >> 1) * 4 + (us & 1) * 2 + b] = h;
      ws[OFF_ENC + (((size_t)(b ? b1 : b0) * TT + t) * HEE + jj)] = h;
    }
    __syncthreads();
  }
}

// ---------------- encW[b][t] = enc[b,t,:] . W_fc[:256] ----------------
__global__ __launch_bounds__(256) void k_encw(const float* __restrict__ W_fc, float* __restrict__ ws) {
  const float* __restrict__ enc = ws + OFF_ENC;
  const int wv = threadIdx.x >> 6, lane = threadIdx.x & 63;
  float4 wfc = reinterpret_cast<const float4*>(W_fc)[lane];
  for (int r = blockIdx.x * 4 + wv; r < BB * TT; r += 4096) {
    float4 e = reinterpret_cast<const float4*>(enc + (size_t)r * HEE)[lane];
    float d = e.x * wfc.x + e.y * wfc.y + e.z * wfc.z + e.w * wfc.w;
    #pragma unroll
    for (int dd = 1; dd < 64; dd <<= 1) d += __shfl_xor(d, dd);
    if (lane == 0) ws[OFF_ENCW + r] = d;
  }
}

// ---------------- enc_proj fp16: epH[b][t'][h] ----------------
__global__ __launch_bounds__(256) void k_encproj(const float* __restrict__ W_d1, float* __restrict__ ws) {
  __shared__ __align__(16) float le[16][256];
  const int tid = threadIdx.x;
  const int b = blockIdx.x >> 4;
  const int t0 = (blockIdx.x & 15) * 16;
  const float* __restrict__ enc = ws + OFF_ENC;
  __half* __restrict__ epH = (__half*)(ws + OFF_EPI);
  #pragma unroll
  for (int rr = 0; rr < 16; ++rr)
    le[rr][tid] = enc[((size_t)b * TT + (t0 + rr)) * HEE + tid];
  __syncthreads();
  const float4* wrow = (const float4*)(W_d1 + (size_t)tid * 768 + 512);
  float acc[16];
  #pragma unroll
  for (int r = 0; r < 16; ++r) acc[r] = 0.f;
  for (int e4 = 0; e4 < 64; ++e4) {
    float4 w = wrow[e4];
    #pragma unroll
    for (int r = 0; r < 16; ++r) {
      float4 ev = *(const float4*)&le[r][e4 * 4];
      acc[r] += ev.x * w.x + ev.y * w.y + ev.z * w.z + ev.w * w.w;
    }
  }
  #pragma unroll
  for (int rr = 0; rr < 16; ++rr)
    epH[((size_t)b * TT + (t0 + rr)) * HEE + tid] = __float2half(acc[rr]);
}

// ---------------- decoder: 1024 threads, 2 batch rows, 255 steps ----------------
__global__ __launch_bounds__(1024, 2) void k_decoder(
    const float* __restrict__ y_history, const float* __restrict__ b_d1,
    const float* __restrict__ W_d2, const float* __restrict__ b_d2,
    const float* __restrict__ W_fc, const float* __restrict__ b_fc,
    const float* __restrict__ bih_d, const float* __restrict__ bhh_d,
    const float* __restrict__ W_ff, const float* __restrict__ b_ff,
    float* __restrict__ ws, float* __restrict__ out) {
  __shared__ __align__(16) ushort epL[65536];   // b0 enc_proj, swizzled, 128 KB
  __shared__ __align__(16) float arena[4096];   // pp / qp / gp / cp (16 KB)
  __shared__ __align__(16) float hcat[1024];    // [h;c] packed 2k+b
  __shared__ __align__(16) float ub2[2][260];   // per-batch LSTM input: [0]=y, [1+j]=h
  __shared__ __align__(16) float ddp2[512];     // d packed 2h+b
  __shared__ __align__(16) ushort w2h[256];     // W_d2 fp16
  __shared__ __align__(16) float ybuf[512];     // y*wfcy+bfc, 2s+b
  __shared__ __align__(16) float awls[512];     // last-step aw, 2t+b
  __shared__ float red[3][8];
  const int tid = threadIdx.x;
  const int tp = tid & 255, q = tid >> 8;
  const int lane = tid & 63, wvid = tid >> 6;
  const int b0 = blockIdx.x * 2, b1 = b0 + 1;

  const float wfcy = W_fc[256], bfc = b_fc[0], bd2v = b_d2[0];
  hcat[tid] = 0.f;
  if (tid < 520) ((float*)ub2)[tid] = 0.f;
  if (tid < 256) w2h[tid] = __half_as_ushort(__float2half(W_d2[tid]));
  if (tid < 510) {
    int s = tid >> 1, b = tid & 1;
    ybuf[tid] = y_history[(size_t)(b ? b1 : b0) * 255 + s] * wfcy + bfc;
  }
  float bd1r = 0.f; float4 biasd = {0, 0, 0, 0};
  if (tid < 512) {
    bd1r = b_d1[tp];
    biasd.x = bih_d[tp] + bhh_d[tp];
    biasd.y = bih_d[256 + tp] + bhh_d[256 + tp];
    biasd.z = bih_d[512 + tp] + bhh_d[512 + tp];
    biasd.w = bih_d[768 + tp] + bhh_d[768 + tp];
  }
  float ewr = 0.f;
  if (q < 2) ewr = ws[OFF_ENCW + (size_t)(q ? b1 : b0) * 256 + tp];

  // ---- load enc_proj: b0 -> swizzled LDS, b1 -> regs ----
  const uint4* __restrict__ epg = (const uint4*)(ws + OFF_EPI);
  {
    const uint4* src = epg + (size_t)b0 * 8192;
    uint4* dst = (uint4*)epL;
    #pragma unroll
    for (int k = 0; k < 8; ++k) {
      int g = k * 1024 + tid;
      int t = g >> 5, c = g & 31;
      dst[(g & ~31) | (c ^ (t & 31))] = src[g];
    }
  }
  uint4 epr[8];
  {
    const uint4* s1 = epg + (size_t)b1 * 8192 + tp * 32 + q * 8;
    #pragma unroll
    for (int k = 0; k < 8; ++k) epr[k] = s1[k];
  }

  const __half2* __restrict__ Wd2h = (const __half2*)(ws + OFF_W2D1);
  const uint4* __restrict__ Wd8 = (const uint4*)(ws + OFF_WD8);
  float4* __restrict__ arena4 = (float4*)arena;
  const uint4* __restrict__ ep16 = (const uint4*)epL;
  __syncthreads();

  for (int s = 0; s < 255; ++s) {
    // ---- p1: d = [h;c].W_d1hc^T partials ----
    {
      float a0 = 0.f, a1 = 0.f;
      const int kb = q * 64;
      #pragma unroll 8
      for (int i = 0; i < 64; ++i) {
        int k2 = kb + i;
        float2 wf = __half22float2(Wd2h[k2 * 256 + tp]);
        float4 hv = *(const float4*)&hcat[k2 * 4];
        a0 = fmaf(wf.x, hv.x, fmaf(wf.y, hv.z, a0));
        a1 = fmaf(wf.x, hv.y, fmaf(wf.y, hv.w, a1));
      }
      arena[(q * 256 + tp) * 2 + 0] = a0;
      arena[(q * 256 + tp) * 2 + 1] = a1;
    }
    __syncthreads();
    if (tid < 512) {
      int b = tid >> 8, h = tid & 255;
      float d = arena[(0 * 256 + h) * 2 + b] + arena[(1 * 256 + h) * 2 + b] +
                arena[(2 * 256 + h) * 2 + b] + arena[(3 * 256 + h) * 2 + b] + bd1r;
      ddp2[2 * h + b] = d;
    }
    __syncthreads();
    // ---- p2: score partials (b0 from LDS, b1 from regs) ----
    {
      float q0 = 0.f, q1 = 0.f;
      const int rowbase = tp * 32, sw = tp & 31;
      #pragma unroll
      for (int k = 0; k < 8; ++k) {
        uint4 e0u = ep16[rowbase + ((q * 8 + k) ^ sw)];
        uint4 e1u = epr[k];
        const int h8 = q * 64 + k * 8;
        uint4 w2u = *(const uint4*)&w2h[h8];
        const __half2* e0h = (const __half2*)&e0u;
        const __half2* e1h = (const __half2*)&e1u;
        const __half2* w2p = (const __half2*)&w2u;
        #pragma unroll
        for (int jj = 0; jj < 4; ++jj) {
          float2 ea = __half22float2(e0h[jj]);
          float2 eb = __half22float2(e1h[jj]);
          float2 wf = __half22float2(w2p[jj]);
          float4 dv = *(const float4*)&ddp2[2 * (h8 + 2 * jj)];
          q0 += wf.x * ftanh(ea.x + dv.x) + wf.y * ftanh(ea.y + dv.z);
          q1 += wf.x * ftanh(eb.x + dv.y) + wf.y * ftanh(eb.y + dv.w);
        }
      }
      arena[(q * 256 + tp) * 2 + 0] = q0;
      arena[(q * 256 + tp) * 2 + 1] = q1;
    }
    __syncthreads();
    // ---- p3: softmax over t' (q<2 active, b=q) ----
    float vsc = 0.f, esc = 0.f;
    if (q < 2) {
      vsc = arena[(0 * 256 + tp) * 2 + q] + arena[(1 * 256 + tp) * 2 + q] +
            arena[(2 * 256 + tp) * 2 + q] + arena[(3 * 256 + tp) * 2 + q] + bd2v;
      float mx = vsc;
      #pragma unroll
      for (int d = 1; d < 64; d <<= 1) mx = fmaxf(mx, __shfl_xor(mx, d));
      if (lane == 0) red[0][wvid] = mx;
    }
    __syncthreads();
    if (q < 2) {
      float mx = fmaxf(fmaxf(red[0][q * 4 + 0], red[0][q * 4 + 1]),
                       fmaxf(red[0][q * 4 + 2], red[0][q * 4 + 3]));
      esc = __expf(vsc - mx);
      float den = esc, num = esc * ewr;
      #pragma unroll
      for (int d = 1; d < 64; d <<= 1) { den += __shfl_xor(den, d); num += __shfl_xor(num, d); }
      if (lane == 0) { red[1][wvid] = den; red[2][wvid] = num; }
    }
    __syncthreads();
    if (q < 2) {
      float den = red[1][q * 4 + 0] + red[1][q * 4 + 1] + red[1][q * 4 + 2] + red[1][q * 4 + 3];
      float num = red[2][q * 4 + 0] + red[2][q * 4 + 1] + red[2][q * 4 + 2] + red[2][q * 4 + 3];
      float inv = frcp(den);
      if (tp == 0) ub2[q][0] = num * inv + ybuf[2 * s + q];
      if (s == 254) awls[2 * tp + q] = esc * inv;
    }
    __syncthreads();
    // ---- p5: decoder LSTM gate partials (per-batch, 2-way k2 split) ----
    {
      const int b = q >> 1, half = q & 1;
      const float* ub = ub2[b];
      const int kA = half ? 65 : 0, kB = half ? 129 : 65;
      float4 g = {0, 0, 0, 0};
      #pragma unroll 4
      for (int k2 = kA; k2 < kB; ++k2) {
        uint4 wu = Wd8[k2 * 256 + tp];
        const __half2* wh = (const __half2*)&wu;
        float2 ife = __half22float2(wh[0]);
        float2 goe = __half22float2(wh[1]);
        float2 ifo = __half22float2(wh[2]);
        float2 goo = __half22float2(wh[3]);
        float2 uv = *(const float2*)&ub[2 * k2];
        g.x = fmaf(ife.x, uv.x, fmaf(ifo.x, uv.y, g.x));
        g.y = fmaf(ife.y, uv.x, fmaf(ifo.y, uv.y, g.y));
        g.z = fmaf(goe.x, uv.x, fmaf(goo.x, uv.y, g.z));
        g.w = fmaf(goe.y, uv.x, fmaf(goo.y, uv.y, g.w));
      }
      arena4[q * 256 + tp] = g;
    }
    __syncthreads();
    if (tid < 512) {
      int b = tid >> 8, jj = tid & 255;
      float4 ga = arena4[(b * 2 + 0) * 256 + jj];
      float4 gb = arena4[(b * 2 + 1) * 256 + jj];
      float gi = ga.x + gb.x + biasd.x, gf = ga.y + gb.y + biasd.y;
      float gg = ga.z + gb.z + biasd.z, go = ga.w + gb.w + biasd.w;
      float cold = hcat[2 * (256 + jj) + b];
      float c = fsig(gf) * cold + fsig(gi) * ftanh(gg);
      float h = fsig(go) * ftanh(c);
      hcat[2 * jj + b] = h;
      hcat[2 * (256 + jj) + b] = c;
      ub2[b][1 + jj] = h;
    }
    __syncthreads();
  }

  // ---- final: ctx with last-step aw + output ----
  {
    float c0 = 0.f, c1 = 0.f;
    const float* __restrict__ e0p = ws + OFF_ENC + (size_t)b0 * TT * HEE;
    const float* __restrict__ e1p = ws + OFF_ENC + (size_t)b1 * TT * HEE;
    for (int t = q * 64; t < q * 64 + 64; ++t) {
      float2 aw = *(const float2*)&awls[2 * t];
      c0 = fmaf(aw.x, e0p[(size_t)t * HEE + tp], c0);
      c1 = fmaf(aw.y, e1p[(size_t)t * HEE + tp], c1);
    }
    arena[(q * 256 + tp) * 2 + 0] = c0;
    arena[(q * 256 + tp) * 2 + 1] = c1;
  }
  __syncthreads();
  if (tid < 512) {
    int b = tid >> 8, h = tid & 255;
    float ctx = arena[(0 * 256 + h) * 2 + b] + arena[(1 * 256 + h) * 2 + b] +
                arena[(2 * 256 + h) * 2 + b] + arena[(3 * 256 + h) * 2 + b];
    float hfin = hcat[2 * h + b];
    float p = hfin * W_ff[h] + ctx * W_ff[256 + h];
    #pragma unroll
    for (int d = 1; d < 64; d <<= 1) p += __shfl_xor(p, d);
    if (lane == 0) red[0][wvid] = p;
  }
  __syncthreads();
  if (tid == 0)   out[b0] = red[0][0] + red[0][1] + red[0][2] + red[0][3] + b_ff[0];
  if (tid == 256) out[b1] = red[0][4] + red[0][5] + red[0][6] + red[0][7] + b_ff[0];
}

extern "C" void kernel_launch(void* const* d_in, const int* in_sizes, int n_in,
                              void* d_out, int out_size, void* d_ws, size_t ws_size,
                              hipStream_t stream) {
  if (ws_size < (size_t)WS_FLOATS * sizeof(float)) return;
  const float* x     = (const float*)d_in[0];
  const float* y_h   = (const float*)d_in[1];
  const float* W_ah  = (const float*)d_in[2];
  const float* b_ah  = (const float*)d_in[3];
  const float* W_ai  = (const float*)d_in[4];
  const float* b_ai  = (const float*)d_in[5];
  const float* W_a   = (const float*)d_in[6];
  const float* b_a   = (const float*)d_in[7];
  const float* Wih_e = (const float*)d_in[8];
  const float* Whh_e = (const float*)d_in[9];
  const float* bih_e = (const float*)d_in[10];
  const float* bhh_e = (const float*)d_in[11];
  const float* W_d1  = (const float*)d_in[12];
  const float* b_d1  = (const float*)d_in[13];
  const float* W_d2  = (const float*)d_in[14];
  const float* b_d2  = (const float*)d_in[15];
  const float* W_fc  = (const float*)d_in[16];
  const float* b_fc  = (const float*)d_in[17];
  const float* Wih_d = (const float*)d_in[18];
  const float* Whh_d = (const float*)d_in[19];
  const float* bih_d = (const float*)d_in[20];
  const float* bhh_d = (const float*)d_in[21];
  const float* W_ff  = (const float*)d_in[22];
  const float* b_ff  = (const float*)d_in[23];
  float* ws  = (float*)d_ws;
  float* out = (float*)d_out;

  k_prep<<<256, 512, 0, stream>>>(W_ah, Wih_e, Whh_e, W_d1, Wih_d, Whh_d, ws);
  k_attn<<<512, 128, 0, stream>>>(x, W_ai, b_ai, ws);
  k_encoder<<<256, 1024, 0, stream>>>(x, b_ah, W_a, b_a, bih_e, bhh_e, ws);
  k_encw<<<1024, 256, 0, stream>>>(W_fc, ws);
  k_encproj<<<8192, 256, 0, stream>>>(W_d1, ws);
  k_decoder<<<256, 1024, 0, stream>>>(y_h, b_d1, W_d2, b_d2, W_fc, b_fc,
                                      bih_d, bhh_d, W_ff, b_ff, ws, out);
}